// Round 3
// baseline (661.766 us; speedup 1.0000x reference)
//
#include <hip/hip_runtime.h>
#include <stdint.h>

#define LOGZERO (-1e10f)

static constexpr int BS    = 32;
static constexpr int XMAX  = 1024;
static constexpr int VOCAB = 1000;
static constexpr int YMAX  = 128;
static constexpr int NROWS = YMAX + 1;     // 129 trigger-mask rows
static constexpr int LPROW = 260;          // padded staged row (float4-aligned)
static constexpr int D     = 8;            // prefetch ring depth
static constexpr int NPAIR = XMAX / 2;

// ---------------- Kernel A: parallel gather into state-ordered lp rows ------
__global__ __launch_bounds__(256) void k_gather(
    const float* __restrict__ ctc, const int* __restrict__ src_size,
    const int* __restrict__ ys, const int* __restrict__ blankp,
    float* __restrict__ lp)
{
    __shared__ int ysl[YMAX];
    const int b    = blockIdx.x >> 8;
    const int t    = ((blockIdx.x & 255) << 2) + (threadIdx.x >> 6);
    const int lane = threadIdx.x & 63;
    if (threadIdx.x < YMAX) ysl[threadIdx.x] = ys[b * YMAX + threadIdx.x];
    __syncthreads();
    if (t >= src_size[b]) return;          // rows t>=ss never read downstream
    const int bv = blankp[0];
    const float* row = ctc + ((size_t)b * XMAX + t) * VOCAB;
    float* orow      = lp  + ((size_t)b * XMAX + t) * LPROW;
    const int l0 = lane, l1 = 64 + lane, l2 = 128 + lane, l3 = 192 + lane;
    float v0 = row[(l0 & 1) ? ysl[l0 >> 1] : bv];
    float v1 = row[(l1 & 1) ? ysl[l1 >> 1] : bv];
    float v2 = row[(l2 & 1) ? ysl[l2 >> 1] : bv];
    float v3 = row[(l3 & 1) ? ysl[l3 >> 1] : bv];
    orow[l0] = v0; orow[l1] = v1; orow[l2] = v2; orow[l3] = v3;
    if (lane == 0) orow[256] = row[bv];
}

// ---------------- Kernel B: per-batch Viterbi + pair-compose + backtrace ----
// Layout: lane i holds states 4i..4i+3; state 256 wave-uniform.
template<int STAGED>
__global__ __launch_bounds__(64) void k_viterbi(
    const float* __restrict__ ctc, const float* __restrict__ lp,
    const int* __restrict__ src_size, const int* __restrict__ ys,
    const int* __restrict__ ylens, const int* __restrict__ blankp,
    int* __restrict__ csum_ws, float* __restrict__ out)
{
    __shared__ unsigned char  bpb[XMAX * 64];      // 64 KB raw 2-bit args x4
    __shared__ unsigned char  bp256[XMAX];         //  1 KB state-256 raw arg
    __shared__ unsigned short bp2[NPAIR * 64];     // 64 KB composed pair nibbles
    __shared__ unsigned char  bp2_256[NPAIR];      // 512 B state-256 pairs
    __shared__ unsigned short st_lds[XMAX];        //  2 KB backtraced states
    __shared__ int ysl[YMAX];

    const int b    = blockIdx.x;
    const int lane = threadIdx.x;
    const int ss   = src_size[b];
    const int yl   = ylens[b];
    const int bv   = blankp[0];
    const int plen = 2 * yl + 1;
    const float LZ = LOGZERO;

    for (int j = lane; j < YMAX; j += 64) ysl[j] = ys[b * YMAX + j];
    for (int t = lane; t < XMAX; t += 64) st_lds[t] = 0;
    __syncthreads();

    const int tokA = ysl[2 * lane];                // state 4i+1
    const int tokB = ysl[2 * lane + 1];            // state 4i+3
    const bool al1 = (lane > 0) && (tokA != ysl[2 * lane - 1]);
    const bool al3 = (tokB != tokA);
    const bool o0 = (4 * lane     >= plen);
    const bool o1 = (4 * lane + 1 >= plen);
    const bool o2 = (4 * lane + 2 >= plen);
    const bool o3 = (4 * lane + 3 >= plen);
    const bool o4 = (256 >= plen);

    float a0 = (lane == 0) ? 0.0f : LZ;
    float a1 = LZ, a2 = LZ, a3 = LZ, a4 = LZ;

    const float* baseg = ctc + (size_t)b * XMAX * VOCAB;
    const float* basel = lp  + (size_t)b * XMAX * LPROW;

    float4 rQ[D]; float rS[D];                 // staged path
    float  rB[D], r1[D], r3[D];                // fallback path
    #pragma unroll
    for (int d = 0; d < D; ++d) {
        int t = (d < ss) ? d : (ss - 1);
        if (STAGED) {
            const float* r = basel + (size_t)t * LPROW;
            rQ[d] = *(const float4*)(r + 4 * lane);
            rS[d] = r[256];
        } else {
            const float* r = baseg + (size_t)t * VOCAB;
            rB[d] = r[bv]; r1[d] = r[tokA]; r3[d] = r[tokB];
        }
    }

    const int ntile = (ss + D - 1) / D;
    for (int tile = 0; tile < ntile; ++tile) {
        #pragma unroll
        for (int d = 0; d < D; ++d) {
            const int t = tile * D + d;
            float lp0, lp1, lp2, lp3, lp4;
            if (STAGED) {
                float4 q = rQ[d];
                lp0 = q.x; lp1 = q.y; lp2 = q.z; lp3 = q.w; lp4 = rS[d];
                int tn = t + D; if (tn >= ss) tn = ss - 1;
                const float* r = basel + (size_t)tn * LPROW;
                rQ[d] = *(const float4*)(r + 4 * lane);
                rS[d] = r[256];
            } else {
                lp0 = rB[d]; lp1 = r1[d]; lp2 = rB[d]; lp3 = r3[d]; lp4 = rB[d];
                int tn = t + D; if (tn >= ss) tn = ss - 1;
                const float* r = baseg + (size_t)tn * VOCAB;
                rB[d] = r[bv]; r1[d] = r[tokA]; r3[d] = r[tokB];
            }
            if (t < ss) {
                float p3 = __shfl_up(a3, 1);
                p3 = (lane == 0) ? LZ : p3;
                float a3_63 = __shfl(a3, 63);

                // strict '>' replicates jnp.argmax first-max tie-break
                float m0 = a0; int g0 = 0; if (p3 > m0) { m0 = p3; g0 = 1; }
                float m1 = a1; int g1 = 0; if (a0 > m1) { m1 = a0; g1 = 1; }
                float sk1 = al1 ? p3 : LZ;  if (sk1 > m1) { m1 = sk1; g1 = 2; }
                float m2 = a2; int g2 = 0; if (a1 > m2) { m2 = a1; g2 = 1; }
                float m3 = a3; int g3 = 0; if (a2 > m3) { m3 = a2; g3 = 1; }
                float sk3 = al3 ? a1 : LZ;  if (sk3 > m3) { m3 = sk3; g3 = 2; }
                float m4 = a4; int g4 = 0; if (a3_63 > m4) { m4 = a3_63; g4 = 1; }

                a0 = (o0 ? LZ : m0) + lp0;
                a1 = (o1 ? LZ : m1) + lp1;
                a2 = (o2 ? LZ : m2) + lp2;
                a3 = (o3 ? LZ : m3) + lp3;
                a4 = (o4 ? LZ : m4) + lp4;

                bpb[t * 64 + lane] =
                    (unsigned char)(g0 | (g1 << 2) | (g2 << 4) | (g3 << 6));
                if (lane == 0) bp256[t] = (unsigned char)g4;
            }
        }
    }
    __syncthreads();

    // ---- score & start state (shuffle extraction, no LDS) ----
    auto getA = [&](int idx) -> float {
        if (idx == 256) return a4;                 // uniform
        int k = idx & 3;                           // idx is wave-uniform
        float pick = (k == 0) ? a0 : (k == 1) ? a1 : (k == 2) ? a2 : a3;
        return __shfl(pick, idx >> 2);
    };
    const float s1v = getA(plen - 1), s2v = getA(plen - 2);
    const float score = (s1v > s2v) ? s1v : s2v;
    const int start = (s1v > s2v) ? (plen - 1) : (plen - 2);
    if (lane == 0) {
        out[b] = score;                                         // output 0
        out[32 + (size_t)BS * NROWS * XMAX + b] = (float)(yl + 1);  // output 2
    }

    // ---- parallel pair-composition: nibble = (a_t, a_{t-1}(s - a_t)) ----
    const int pmax = (ss - 1) >> 1;            // pairs used: p in [1, pmax]
    for (int p = 1; p <= pmax; ++p) {
        int oOdd  = bpb[(2 * p + 1) * 64 + lane];
        int oEven = bpb[(2 * p) * 64 + lane];
        int uEven = (lane > 0) ? bpb[(2 * p) * 64 + lane - 1] : 0;
        int evenWin = uEven | (oEven << 8);    // states 4l-4..4l+3 of even row
        unsigned int acc = 0;
        #pragma unroll
        for (int k = 0; k < 4; ++k) {
            int a1v = (oOdd >> (2 * k)) & 3;
            int sh  = 2 * k - 2 * a1v + 8;     // bit pos of state s-a1 in window
            int a2v = (evenWin >> sh) & 3;
            acc |= (unsigned)(a1v | (a2v << 2)) << (4 * k);
        }
        bp2[p * 64 + lane] = (unsigned short)acc;
        int a16 = bp256[2 * p + 1];
        int a26 = (a16 == 0) ? bp256[2 * p] : ((bpb[(2 * p) * 64 + 63] >> 6) & 3);
        if (lane == 0) bp2_256[p] = (unsigned char)(a16 | (a26 << 2));
    }
    __syncthreads();

    // ---- backtrace: 2 steps per dependent LDS read ----
    if (lane == 0) {
        int s = start, tc = ss - 1;
        st_lds[tc] = (unsigned short)s;
        if ((tc & 1) == 0 && tc >= 1) {        // raw single step on even row tc
            int arg;
            if (s == 256) arg = bp256[tc];
            else arg = (bpb[tc * 64 + (s >> 2)] >> ((s & 3) * 2)) & 3;
            s -= arg; --tc; st_lds[tc] = (unsigned short)s;
        }
        while (tc > 1) {                        // tc odd: pair p = tc>>1
            int n;
            if (s == 256) n = bp2_256[tc >> 1];
            else n = (bp2[(tc >> 1) * 64 + (s >> 2)] >> ((s & 3) * 4)) & 0xF;
            int sA = s - (n & 3);
            int sB = sA - (n >> 2);
            st_lds[tc - 1] = (unsigned short)sA;
            st_lds[tc - 2] = (unsigned short)sB;
            s = sB; tc -= 2;
        }
        if (tc == 1) {                          // raw row 1
            int arg;
            if (s == 256) arg = bp256[1];
            else arg = (bpb[64 + (s >> 2)] >> ((s & 3) * 2)) & 3;
            s -= arg; st_lds[0] = (unsigned short)s;
        }
    }
    __syncthreads();

    // ---- aligned tokens -> collapse repeats -> csum ----
    auto tok_lds = [&](int stv) -> int { return (stv & 1) ? ysl[stv >> 1] : bv; };
    const int t0 = lane * 16;
    int prev_raw = (t0 == 0) ? 0 : tok_lds(st_lds[t0 - 1]);
    int cnt = 0;
    int csl[16];
    #pragma unroll
    for (int i = 0; i < 16; ++i) {
        int raw = tok_lds(st_lds[t0 + i]);
        int ac = (raw == prev_raw) ? 0 : raw;
        prev_raw = raw;
        csl[i] = cnt;
        cnt += (ac != bv) ? 1 : 0;
    }
    int v = cnt;
    #pragma unroll
    for (int off = 1; off < 64; off <<= 1) {
        int u = __shfl_up(v, off);
        if (lane >= off) v += u;
    }
    const int base_c = v - cnt;
    int* co = csum_ws + b * XMAX + t0;
    #pragma unroll
    for (int i = 0; i < 16; ++i) co[i] = base_c + csl[i];
}

// ---------------- Kernel C: trigger mask as 0/1 floats ----------------------
__global__ __launch_bounds__(256) void k_mask(
    const int* __restrict__ csum_ws, const int* __restrict__ src_size,
    float* __restrict__ out)
{
    int bj = blockIdx.x;
    int b = bj / NROWS, j = bj - b * NROWS;
    int ss = src_size[b];
    const int* cs = csum_ws + b * XMAX;
    float* orow = out + 32 + (size_t)bj * XMAX;
    int t = threadIdx.x * 4;
    float4 v;
    float* vp = &v.x;
    #pragma unroll
    for (int i = 0; i < 4; ++i) {
        int tt = t + i;
        int c = cs[tt];
        bool in = tt < ss;
        bool val;
        if (j < YMAX) val = (c == j) && in;
        else          val = ((c == YMAX) || (tt == ss - 1)) && in;
        vp[i] = val ? 1.0f : 0.0f;
    }
    *(float4*)(orow + t) = v;
}

extern "C" void kernel_launch(void* const* d_in, const int* in_sizes, int n_in,
                              void* d_out, int out_size, void* d_ws, size_t ws_size,
                              hipStream_t stream) {
    const float* ctc      = (const float*)d_in[0];
    // d_in[1] = src_mask (derived from src_size; unused)
    const int*   src_size = (const int*)d_in[2];
    const int*   ys       = (const int*)d_in[3];
    const int*   ylens    = (const int*)d_in[4];
    const int*   blankp   = (const int*)d_in[5];
    float* out = (float*)d_out;

    size_t lp_bytes = (size_t)BS * XMAX * LPROW * sizeof(float);   // ~34 MB
    size_t cs_bytes = (size_t)BS * XMAX * sizeof(int);
    int staged = (ws_size >= lp_bytes + cs_bytes) ? 1 : 0;
    float* lp_path = (float*)d_ws;
    int*   csum_ws = staged ? (int*)((char*)d_ws + lp_bytes) : (int*)d_ws;

    if (staged) {
        k_gather<<<BS * 256, 256, 0, stream>>>(ctc, src_size, ys, blankp, lp_path);
        k_viterbi<1><<<BS, 64, 0, stream>>>(ctc, lp_path, src_size, ys, ylens,
                                            blankp, csum_ws, out);
    } else {
        k_viterbi<0><<<BS, 64, 0, stream>>>(ctc, lp_path, src_size, ys, ylens,
                                            blankp, csum_ws, out);
    }
    k_mask<<<BS * NROWS, 256, 0, stream>>>(csum_ws, src_size, out);
}

// Round 4
// 354.301 us; speedup vs baseline: 1.8678x; 1.8678x over previous
//
#include <hip/hip_runtime.h>
#include <stdint.h>

#define LOGZERO (-1e10f)

static constexpr int BS    = 32;
static constexpr int XMAX  = 1024;
static constexpr int VOCAB = 1000;
static constexpr int YMAX  = 128;
static constexpr int NROWS = YMAX + 1;     // 129 trigger-mask rows
static constexpr int CH    = 8;            // rows per LDS chunk
static constexpr int NPROD = 8;            // producer waves
static constexpr int NWAVES = 1 + NPROD;   // + 1 consumer wave
static constexpr int NPAIR = XMAX / 2;

// ---------------- Kernel B: producer/consumer Viterbi + backtrace + csum ----
// Consumer wave (wid 0): lane i holds states 4i..4i+3; state 256 on lane 0.
// Producer waves (wid 1..8): gather ctc rows into double-buffered LDS ring.
__global__ __launch_bounds__(64 * NWAVES) void k_viterbi(
    const float* __restrict__ ctc, const int* __restrict__ src_size,
    const int* __restrict__ ys, const int* __restrict__ ylens,
    const int* __restrict__ blankp, int* __restrict__ csum_ws,
    float* __restrict__ out)
{
    __shared__ float buf[2][CH][256];              // 16 KB lp ring
    __shared__ unsigned char  bpb[XMAX * 64];      // 64 KB raw 2-bit args x4
    __shared__ unsigned char  bp256[XMAX];         //  1 KB state-256 raw arg
    __shared__ unsigned short bp2[NPAIR * 64];     // 64 KB composed pair nibbles
    __shared__ unsigned char  bp2_256[NPAIR];      // 512 B state-256 pairs
    __shared__ unsigned short st_lds[XMAX];        //  2 KB backtraced states
    __shared__ int ysl[YMAX];

    const int b    = blockIdx.x;
    const int tid  = threadIdx.x;
    const int wid  = tid >> 6;
    const int lane = tid & 63;
    const int ss   = src_size[b];
    const int yl   = ylens[b];
    const int bv   = blankp[0];
    const int plen = 2 * yl + 1;
    const float LZ = LOGZERO;

    for (int j = tid; j < YMAX; j += 64 * NWAVES) ysl[j] = ys[b * YMAX + j];
    for (int t = tid; t < XMAX; t += 64 * NWAVES) st_lds[t] = 0;
    __syncthreads();

    const int nchunk = (ss + CH - 1) / CH;
    const float* baseg = ctc + (size_t)b * XMAX * VOCAB;

    int start = 0;   // set by consumer wave, used by lane 0 chain later

    if (wid == 0) {
        // ---------------- consumer ----------------
        const bool al1 = (lane > 0) && (ysl[2 * lane] != ysl[2 * lane - 1]);
        const bool al3 = (ysl[2 * lane + 1] != ysl[2 * lane]);
        const bool o0 = (4 * lane     >= plen);
        const bool o1 = (4 * lane + 1 >= plen);
        const bool o2 = (4 * lane + 2 >= plen);
        const bool o3 = (4 * lane + 3 >= plen);
        const bool o4 = (256 >= plen);
        const int rotidx = (lane + 63) & 63;

        float a0 = (lane == 0) ? 0.0f : LZ;
        float a1 = LZ, a2 = LZ, a3 = LZ, a4 = LZ;

        for (int c = 0; c < nchunk; ++c) {
            __syncthreads();                       // ring chunk c ready
            const int cb = c & 1;
            float4 q[CH];
            #pragma unroll
            for (int r = 0; r < CH; ++r)
                q[r] = *reinterpret_cast<const float4*>(&buf[cb][r][lane * 4]);
            #pragma unroll
            for (int r = 0; r < CH; ++r) {
                const int t = c * CH + r;
                if (t < ss) {
                    float rot = __shfl(a3, rotidx);        // lane i: a3[i-1]; lane0: a3[63]
                    float p3 = (lane == 0) ? LZ : rot;
                    // strict '>' replicates jnp.argmax first-max tie-break
                    float m0 = a0; int g0 = 0; if (p3 > m0) { m0 = p3; g0 = 1; }
                    float m1 = a1; int g1 = 0; if (a0 > m1) { m1 = a0; g1 = 1; }
                    float sk1 = al1 ? p3 : LZ;  if (sk1 > m1) { m1 = sk1; g1 = 2; }
                    float m2 = a2; int g2 = 0; if (a1 > m2) { m2 = a1; g2 = 1; }
                    float m3 = a3; int g3 = 0; if (a2 > m3) { m3 = a2; g3 = 1; }
                    float sk3 = al3 ? a1 : LZ;  if (sk3 > m3) { m3 = sk3; g3 = 2; }
                    float m4 = a4; int g4 = 0; if (rot > m4) { m4 = rot; g4 = 1; }
                    a0 = (o0 ? LZ : m0) + q[r].x;
                    a1 = (o1 ? LZ : m1) + q[r].y;
                    a2 = (o2 ? LZ : m2) + q[r].z;
                    a3 = (o3 ? LZ : m3) + q[r].w;
                    a4 = (o4 ? LZ : m4) + q[r].x;          // lp4 == blank lp == q.x
                    bpb[t * 64 + lane] =
                        (unsigned char)(g0 | (g1 << 2) | (g2 << 4) | (g3 << 6));
                    if (lane == 0) bp256[t] = (unsigned char)g4;
                }
            }
        }

        // score & start (a4 valid on lane 0 only)
        auto getA = [&](int idx) -> float {
            if (idx == 256) return __shfl(a4, 0);
            int k = idx & 3;
            float pick = (k == 0) ? a0 : (k == 1) ? a1 : (k == 2) ? a2 : a3;
            return __shfl(pick, idx >> 2);
        };
        const float s1v = getA(plen - 1), s2v = getA(plen - 2);
        const float score = (s1v > s2v) ? s1v : s2v;
        start = (s1v > s2v) ? (plen - 1) : (plen - 2);
        if (lane == 0) {
            out[b] = score;                                          // output 0
            out[32 + (size_t)BS * NROWS * XMAX + b] = (float)(yl + 1);   // output 2
        }
    } else {
        // ---------------- producers ----------------
        const int pr = wid - 1;                    // row within chunk
        const int tokA = ysl[2 * lane];
        const int tokB = ysl[2 * lane + 1];
        int t0 = pr; if (t0 >= ss) t0 = ss - 1;
        const float* r0 = baseg + (size_t)t0 * VOCAB;
        float vb = r0[bv], va = r0[tokA], vc = r0[tokB];
        for (int c = 0; c < nchunk; ++c) {
            *reinterpret_cast<float4*>(&buf[c & 1][pr][lane * 4]) =
                make_float4(vb, va, vb, vc);
            int tn = (c + 1) * CH + pr; if (tn >= ss) tn = ss - 1;
            const float* r = baseg + (size_t)tn * VOCAB;
            vb = r[bv]; va = r[tokA]; vc = r[tokB];
            __syncthreads();                       // publish chunk c
        }
    }
    __syncthreads();   // bpb/bp256 visible to all waves

    // ---- parallel pair-composition across all 9 waves ----
    const int pmax = (ss - 1) >> 1;                // pairs used: p in [1, pmax]
    for (int p = 1 + wid; p <= pmax; p += NWAVES) {
        int oOdd  = bpb[(2 * p + 1) * 64 + lane];
        int oEven = bpb[(2 * p) * 64 + lane];
        int uEven = (lane > 0) ? bpb[(2 * p) * 64 + lane - 1] : 0;
        int evenWin = uEven | (oEven << 8);        // states 4l-4..4l+3 of even row
        unsigned int acc = 0;
        #pragma unroll
        for (int k = 0; k < 4; ++k) {
            int a1v = (oOdd >> (2 * k)) & 3;
            int sh  = 2 * k - 2 * a1v + 8;         // bit pos of state s-a1 in window
            int a2v = (evenWin >> sh) & 3;
            acc |= (unsigned)(a1v | (a2v << 2)) << (4 * k);
        }
        bp2[p * 64 + lane] = (unsigned short)acc;
        int a16 = bp256[2 * p + 1];
        int a26 = (a16 == 0) ? bp256[2 * p] : ((bpb[(2 * p) * 64 + 63] >> 6) & 3);
        if (lane == 0) bp2_256[p] = (unsigned char)(a16 | (a26 << 2));
    }
    __syncthreads();

    // ---- backtrace: 2 steps per dependent LDS read (lane 0 of wave 0) ----
    if (tid == 0) {
        int s = start, tc = ss - 1;
        st_lds[tc] = (unsigned short)s;
        if ((tc & 1) == 0 && tc >= 1) {            // raw single step on even row tc
            int arg;
            if (s == 256) arg = bp256[tc];
            else arg = (bpb[tc * 64 + (s >> 2)] >> ((s & 3) * 2)) & 3;
            s -= arg; --tc; st_lds[tc] = (unsigned short)s;
        }
        while (tc > 1) {                           // tc odd: pair p = tc>>1
            int n;
            if (s == 256) n = bp2_256[tc >> 1];
            else n = (bp2[(tc >> 1) * 64 + (s >> 2)] >> ((s & 3) * 4)) & 0xF;
            int sA = s - (n & 3);
            int sB = sA - (n >> 2);
            st_lds[tc - 1] = (unsigned short)sA;
            st_lds[tc - 2] = (unsigned short)sB;
            s = sB; tc -= 2;
        }
        if (tc == 1) {                             // raw row 1
            int arg;
            if (s == 256) arg = bp256[1];
            else arg = (bpb[64 + (s >> 2)] >> ((s & 3) * 2)) & 3;
            s -= arg; st_lds[0] = (unsigned short)s;
        }
    }
    __syncthreads();

    // ---- aligned tokens -> collapse repeats -> csum (wave 0) ----
    if (wid == 0) {
        auto tok_lds = [&](int stv) -> int { return (stv & 1) ? ysl[stv >> 1] : bv; };
        const int t0c = lane * 16;
        int prev_raw = (t0c == 0) ? 0 : tok_lds(st_lds[t0c - 1]);
        int cnt = 0;
        int csl[16];
        #pragma unroll
        for (int i = 0; i < 16; ++i) {
            int raw = tok_lds(st_lds[t0c + i]);
            int ac = (raw == prev_raw) ? 0 : raw;
            prev_raw = raw;
            csl[i] = cnt;
            cnt += (ac != bv) ? 1 : 0;
        }
        int v = cnt;
        #pragma unroll
        for (int off = 1; off < 64; off <<= 1) {
            int u = __shfl_up(v, off);
            if (lane >= off) v += u;
        }
        const int base_c = v - cnt;
        int* co = csum_ws + b * XMAX + t0c;
        #pragma unroll
        for (int i = 0; i < 16; ++i) co[i] = base_c + csl[i];
    }
}

// ---------------- Kernel C: trigger mask as 0/1 floats ----------------------
__global__ __launch_bounds__(256) void k_mask(
    const int* __restrict__ csum_ws, const int* __restrict__ src_size,
    float* __restrict__ out)
{
    int bj = blockIdx.x;
    int b = bj / NROWS, j = bj - b * NROWS;
    int ss = src_size[b];
    const int* cs = csum_ws + b * XMAX;
    float* orow = out + 32 + (size_t)bj * XMAX;
    int t = threadIdx.x * 4;
    float4 v;
    float* vp = &v.x;
    #pragma unroll
    for (int i = 0; i < 4; ++i) {
        int tt = t + i;
        int c = cs[tt];
        bool in = tt < ss;
        bool val;
        if (j < YMAX) val = (c == j) && in;
        else          val = ((c == YMAX) || (tt == ss - 1)) && in;
        vp[i] = val ? 1.0f : 0.0f;
    }
    *(float4*)(orow + t) = v;
}

extern "C" void kernel_launch(void* const* d_in, const int* in_sizes, int n_in,
                              void* d_out, int out_size, void* d_ws, size_t ws_size,
                              hipStream_t stream) {
    const float* ctc      = (const float*)d_in[0];
    // d_in[1] = src_mask (derived from src_size; unused)
    const int*   src_size = (const int*)d_in[2];
    const int*   ys       = (const int*)d_in[3];
    const int*   ylens    = (const int*)d_in[4];
    const int*   blankp   = (const int*)d_in[5];
    float* out = (float*)d_out;
    int*   csum_ws = (int*)d_ws;   // 32*1024*4 = 128 KB

    k_viterbi<<<BS, 64 * NWAVES, 0, stream>>>(ctc, src_size, ys, ylens, blankp,
                                              csum_ws, out);
    k_mask<<<BS * NROWS, 256, 0, stream>>>(csum_ws, src_size, out);
}